// Round 2
// baseline (1110.931 us; speedup 1.0000x reference)
//
#include <hip/hip_runtime.h>
#include <math.h>

#define Bb 16
#define Nn 100
#define Ll 90
#define Dd 300
#define NBLK (Bb*Nn)
#define LP 96
#define DP 320
#define DPH 40   // DP/8 16-byte chunks per row

typedef __attribute__((ext_vector_type(8))) short short8v;
typedef __attribute__((ext_vector_type(4))) short short4v;
typedef __attribute__((ext_vector_type(4))) float f32x4;

__device__ __forceinline__ unsigned short f2bf(float f) {
  unsigned int u = __float_as_uint(f);
  u += 0x7fffu + ((u >> 16) & 1u);
  return (unsigned short)(u >> 16);
}
__device__ __forceinline__ float bf2f(unsigned short h) {
  return __uint_as_float(((unsigned int)h) << 16);
}

// ---------------- setup kernels ----------------
// M[i][j] = sum_o Wq[o][i]*Wk[o][j], bf16, padded to 320x320 with zeros
__global__ __launch_bounds__(256) void k_matM(const float* __restrict__ Wq,
                                              const float* __restrict__ Wk,
                                              unsigned short* __restrict__ Mb) {
  int idx = blockIdx.x * 256 + threadIdx.x;
  if (idx >= DP * DP) return;
  int i = idx / DP, j = idx % DP;
  float s = 0.f;
  if (i < Dd && j < Dd) {
    for (int o = 0; o < Dd; o++) s += Wq[o * Dd + i] * Wk[o * Dd + j];
  }
  Mb[idx] = f2bf(s);
}

// G[o][p] = sum_v Wf[o][v]*Wv[v][p], f32, [300][304] (pad cols zero)
__global__ __launch_bounds__(256) void k_matG(const float* __restrict__ Wf,
                                              const float* __restrict__ Wv,
                                              float* __restrict__ G) {
  int idx = blockIdx.x * 256 + threadIdx.x;
  if (idx >= Dd * 304) return;
  int o = idx / 304, p = idx % 304;
  float s = 0.f;
  if (p < Dd) {
    for (int v = 0; v < Dd; v++) s += Wf[o * Dd + v] * Wv[v * Dd + p];
  }
  G[idx] = s;
}

// u = Wq^T b_k, t = Wk^T b_q, c = b_q.b_k, bias2 = 90*(Wf b_v + b_f)
__global__ void k_vec(const float* __restrict__ Wq, const float* __restrict__ Wk,
                      const float* __restrict__ Wf,
                      const float* __restrict__ bq, const float* __restrict__ bk,
                      const float* __restrict__ bv, const float* __restrict__ bf,
                      float* __restrict__ uv, float* __restrict__ tv,
                      float* __restrict__ cv, float* __restrict__ bias2) {
  int t = threadIdx.x;
  if (t < 304) {
    float su = 0.f, st = 0.f, sb = 0.f;
    if (t < Dd) {
      for (int o = 0; o < Dd; o++) {
        su += Wq[o * Dd + t] * bk[o];
        st += Wk[o * Dd + t] * bq[o];
      }
      for (int v = 0; v < Dd; v++) sb += Wf[t * Dd + v] * bv[v];
      sb = 90.f * (sb + bf[t]);
    }
    uv[t] = su; tv[t] = st; bias2[t] = sb;
  }
  if (t == 511) {
    float s = 0.f;
    for (int o = 0; o < Dd; o++) s += bq[o] * bk[o];
    cv[0] = s;
  }
}

// ---------------- per-(b,n) attention kernel ----------------
__global__ __launch_bounds__(512) void k_attn(
    const float* __restrict__ items, const unsigned short* __restrict__ Mb,
    const float* __restrict__ uvec, const float* __restrict__ tvec,
    const float* __restrict__ cval_p,
    float* __restrict__ r_all, float* __restrict__ colsum_all) {
  __shared__ unsigned short Xs[LP * DP];   // 61440 B, bf16 swizzled
  __shared__ unsigned short ZT[LP * DP];   // 61440 B
  __shared__ float Ss[LP * 100];           // 38400 B
  __shared__ float wsum[96];
  __shared__ float ulv[96];
  __shared__ float tmv[96];

  const int tid = threadIdx.x;
  const int bid = blockIdx.x;
  const float* Xg = items + (size_t)bid * (Ll * Dd);

  // Phase 0: X -> LDS bf16, swizzled, zero-padded to [96][320]
  for (int c = tid; c < LP * DPH; c += 512) {
    int l = c / DPH, ch = c % DPH, d0 = ch * 8;
    float v[8];
    if (l < Ll && d0 < Dd) {
      if (d0 + 8 <= Dd) {
        float4 a = *(const float4*)(Xg + l * Dd + d0);
        float4 b = *(const float4*)(Xg + l * Dd + d0 + 4);
        v[0] = a.x; v[1] = a.y; v[2] = a.z; v[3] = a.w;
        v[4] = b.x; v[5] = b.y; v[6] = b.z; v[7] = b.w;
      } else {
#pragma unroll
        for (int q = 0; q < 8; q++) { int d = d0 + q; v[q] = (d < Dd) ? Xg[l * Dd + d] : 0.f; }
      }
    } else {
#pragma unroll
      for (int q = 0; q < 8; q++) v[q] = 0.f;
    }
    short8v pk;
#pragma unroll
    for (int q = 0; q < 8; q++) pk[q] = (short)f2bf(v[q]);
    int off = l * 640 + ((d0 * 2) ^ ((l & 7) << 4));
    *(short8v*)((char*)Xs + off) = pk;
  }

  // colsum(X) exact f32 from global (L2-hot)
  for (int d = tid; d < 304; d += 512) {
    float s = 0.f;
    if (d < Dd) {
      for (int l = 0; l < Ll; l++) s += Xg[l * Dd + d];
    }
    colsum_all[(size_t)bid * 304 + d] = s;
  }
  __syncthreads();

  // ul[l] = X[l].u ; tm[m] = X[m].t ; zero wsum
  if (tid < 96) {
    int l = tid; float s = 0.f;
    if (l < Ll) {
      for (int i = 0; i < Dd; i++)
        s += bf2f(Xs[(l * 640 + ((i * 2) ^ ((l & 7) << 4))) >> 1]) * uvec[i];
    }
    ulv[l] = s;
  } else if (tid < 192) {
    int m = tid - 96; float s = 0.f;
    for (int i = 0; i < Dd; i++)
      s += bf2f(Xs[(m * 640 + ((i * 2) ^ ((m & 7) << 4))) >> 1]) * tvec[i];
    tmv[m] = s;
  } else if (tid < 288) {
    wsum[tid - 192] = 0.f;
  }

  const int lane = tid & 63, wave = tid >> 6;
  const int fr = lane & 15, kg = lane >> 4;

  // GEMM1: Z[i][m] = sum_j M[i][j] X[m][j]  -> stored transposed ZT[m][i] bf16
  for (int it = wave; it < 20; it += 8) {
    f32x4 acc[6];
#pragma unroll
    for (int mt = 0; mt < 6; mt++) acc[mt] = (f32x4){0.f, 0.f, 0.f, 0.f};
    for (int ks = 0; ks < 10; ks++) {
      short8v a = *(const short8v*)(Mb + ((it * 16 + fr) * DP + ks * 32 + kg * 8));
#pragma unroll
      for (int mt = 0; mt < 6; mt++) {
        int row = mt * 16 + fr;
        short8v b = *(const short8v*)((char*)Xs + row * 640 +
                                      (((ks * 32 + kg * 8) * 2) ^ ((row & 7) << 4)));
        acc[mt] = __builtin_amdgcn_mfma_f32_16x16x32_bf16(a, b, acc[mt], 0, 0, 0);
      }
    }
#pragma unroll
    for (int mt = 0; mt < 6; mt++) {
      int m = mt * 16 + fr;
      int i0 = it * 16 + kg * 4;
      short4v pk;
#pragma unroll
      for (int r2 = 0; r2 < 4; r2++) pk[r2] = (short)f2bf(acc[mt][r2]);
      *(short4v*)((char*)ZT + m * 640 + ((i0 * 2) ^ ((m & 7) << 4))) = pk;
    }
  }
  __syncthreads();

  // GEMM2: S[l][m] = sum_i X[l][i] Z[i][m]
  for (int t36 = wave; t36 < 36; t36 += 8) {
    int lt = t36 / 6, mt = t36 % 6;
    f32x4 acc = (f32x4){0.f, 0.f, 0.f, 0.f};
    for (int ks = 0; ks < 10; ks++) {
      int rowa = lt * 16 + fr;
      short8v a = *(const short8v*)((char*)Xs + rowa * 640 +
                                    (((ks * 32 + kg * 8) * 2) ^ ((rowa & 7) << 4)));
      int rowb = mt * 16 + fr;
      short8v b = *(const short8v*)((char*)ZT + rowb * 640 +
                                    (((ks * 32 + kg * 8) * 2) ^ ((rowb & 7) << 4)));
      acc = __builtin_amdgcn_mfma_f32_16x16x32_bf16(a, b, acc, 0, 0, 0);
    }
#pragma unroll
    for (int r2 = 0; r2 < 4; r2++) {
      int l = lt * 16 + kg * 4 + r2;
      Ss[l * 100 + mt * 16 + fr] = acc[r2];
    }
  }
  __syncthreads();

  // row softmax + column-sum into wsum
  const float cv = cval_p[0];
  for (int row = wave; row < Ll; row += 8) {
    float base = ulv[row] + cv;
    float x0 = 0.1f * (Ss[row * 100 + lane] + base + tmv[lane]);
    int m1 = lane + 64;
    float x1 = (m1 < Ll) ? 0.1f * (Ss[row * 100 + m1] + base + tmv[m1]) : -INFINITY;
    float mx = fmaxf(x0, x1);
#pragma unroll
    for (int o = 32; o; o >>= 1) mx = fmaxf(mx, __shfl_xor(mx, o));
    float e0 = __expf(x0 - mx);
    float e1 = (m1 < Ll) ? __expf(x1 - mx) : 0.f;
    float s = e0 + e1;
#pragma unroll
    for (int o = 32; o; o >>= 1) s += __shfl_xor(s, o);
    float inv = 1.f / s;
    atomicAdd(&wsum[lane], e0 * inv);
    if (m1 < Ll) atomicAdd(&wsum[m1], e1 * inv);
  }
  __syncthreads();

  // r[i] = sum_m w[m] X[m][i]
  for (int i = tid; i < 304; i += 512) {
    float s = 0.f;
    if (i < Dd) {
      for (int m = 0; m < Ll; m++)
        s += wsum[m] * bf2f(Xs[(m * 640 + ((i * 2) ^ ((m & 7) << 4))) >> 1]);
    }
    r_all[(size_t)bid * 304 + i] = s;
  }
}

// ---------------- generic f32 GEMM: C = op(A) @ W^T + bias (+res) ----------------
__global__ __launch_bounds__(256) void k_gemm_bt(
    const float* __restrict__ A, int lda, const float* __restrict__ W, int ldw,
    const float* __restrict__ bias, const float* __restrict__ res, int ldres,
    float* __restrict__ C, int ldc, int Mdim, int Ndim, int Kdim,
    const float* __restrict__ bng, const float* __restrict__ bnb) {
  __shared__ float As[16][68];
  __shared__ float Bs[16][68];
  int m0 = blockIdx.x * 64, n0 = blockIdx.y * 64;
  int tx = threadIdx.x & 15, ty = threadIdx.x >> 4;
  float acc[4][4];
#pragma unroll
  for (int i = 0; i < 4; i++)
#pragma unroll
    for (int j = 0; j < 4; j++) acc[i][j] = 0.f;
  const float bninv = rsqrtf(1.00001f);
  int r = threadIdx.x >> 2;
  int kq = (threadIdx.x & 3) << 2;
  for (int k0 = 0; k0 < Kdim; k0 += 16) {
    {
      int gm = m0 + r;
      float4 v = {0.f, 0.f, 0.f, 0.f};
      if (gm < Mdim) v = *(const float4*)(A + (size_t)gm * lda + k0 + kq);
      if (bng) {
        float4 g = *(const float4*)(bng + k0 + kq);
        float4 bb = *(const float4*)(bnb + k0 + kq);
        v.x = v.x * (g.x * bninv) + bb.x;
        v.y = v.y * (g.y * bninv) + bb.y;
        v.z = v.z * (g.z * bninv) + bb.z;
        v.w = v.w * (g.w * bninv) + bb.w;
      }
      As[kq + 0][r] = v.x; As[kq + 1][r] = v.y; As[kq + 2][r] = v.z; As[kq + 3][r] = v.w;
    }
    {
      int gn = n0 + r;
      float4 v = {0.f, 0.f, 0.f, 0.f};
      if (gn < Ndim) v = *(const float4*)(W + (size_t)gn * ldw + k0 + kq);
      Bs[kq + 0][r] = v.x; Bs[kq + 1][r] = v.y; Bs[kq + 2][r] = v.z; Bs[kq + 3][r] = v.w;
    }
    __syncthreads();
#pragma unroll
    for (int kk = 0; kk < 16; kk++) {
      float4 av = *(const float4*)&As[kk][ty * 4];
      float4 bv = *(const float4*)&Bs[kk][tx * 4];
      acc[0][0] += av.x * bv.x; acc[0][1] += av.x * bv.y; acc[0][2] += av.x * bv.z; acc[0][3] += av.x * bv.w;
      acc[1][0] += av.y * bv.x; acc[1][1] += av.y * bv.y; acc[1][2] += av.y * bv.z; acc[1][3] += av.y * bv.w;
      acc[2][0] += av.z * bv.x; acc[2][1] += av.z * bv.y; acc[2][2] += av.z * bv.z; acc[2][3] += av.z * bv.w;
      acc[3][0] += av.w * bv.x; acc[3][1] += av.w * bv.y; acc[3][2] += av.w * bv.z; acc[3][3] += av.w * bv.w;
    }
    __syncthreads();
  }
#pragma unroll
  for (int i = 0; i < 4; i++) {
    int gm = m0 + ty * 4 + i;
    if (gm >= Mdim) continue;
#pragma unroll
    for (int j = 0; j < 4; j++) {
      int gn = n0 + tx * 4 + j;
      if (gn >= Ndim) continue;
      float v = acc[i][j];
      if (bias) v += bias[gn];
      if (res) v += res[(size_t)gm * ldres + gn];
      C[(size_t)gm * ldc + gn] = v;
    }
  }
}

// ---------------- cosine-sim + masked softmax per batch ----------------
__global__ __launch_bounds__(512) void k_sim(const float* __restrict__ hrev,
                                             const int* __restrict__ adj,
                                             float* __restrict__ simin,
                                             float* __restrict__ simout) {
  __shared__ float hr[Nn * 304];   // 121600 B
  __shared__ float nrm[Nn];
  __shared__ float sm[Nn * Nn];    // 40000 B
  int b = blockIdx.x, tid = threadIdx.x;
  const float* src = hrev + (size_t)b * Nn * 304;
  for (int c = tid; c < Nn * 76; c += 512)
    *(float4*)&hr[c * 4] = *(const float4*)(src + c * 4);
  __syncthreads();
  if (tid < Nn) {
    float s = 0.f;
    for (int i = 0; i < Dd; i++) { float v = hr[tid * 304 + i]; s += v * v; }
    nrm[tid] = sqrtf(s);
  }
  __syncthreads();
  for (int item = tid; item < Nn * 25; item += 512) {
    int n = item / 25, mq = (item % 25) * 4;
    float a0 = 0.f, a1 = 0.f, a2 = 0.f, a3 = 0.f;
    for (int i = 0; i < Dd; i += 4) {
      float4 x = *(const float4*)&hr[n * 304 + i];
      float4 y0 = *(const float4*)&hr[(mq + 0) * 304 + i];
      float4 y1 = *(const float4*)&hr[(mq + 1) * 304 + i];
      float4 y2 = *(const float4*)&hr[(mq + 2) * 304 + i];
      float4 y3 = *(const float4*)&hr[(mq + 3) * 304 + i];
      a0 += x.x * y0.x + x.y * y0.y + x.z * y0.z + x.w * y0.w;
      a1 += x.x * y1.x + x.y * y1.y + x.z * y1.z + x.w * y1.w;
      a2 += x.x * y2.x + x.y * y2.y + x.z * y2.z + x.w * y2.w;
      a3 += x.x * y3.x + x.y * y3.y + x.z * y3.z + x.w * y3.w;
    }
    float nn = nrm[n];
    sm[n * Nn + mq + 0] = a0 / fmaxf(nn * nrm[mq + 0], 1e-8f);
    sm[n * Nn + mq + 1] = a1 / fmaxf(nn * nrm[mq + 1], 1e-8f);
    sm[n * Nn + mq + 2] = a2 / fmaxf(nn * nrm[mq + 2], 1e-8f);
    sm[n * Nn + mq + 3] = a3 / fmaxf(nn * nrm[mq + 3], 1e-8f);
  }
  __syncthreads();
  int lane = tid & 63, wave = tid >> 6;
  for (int n = wave; n < Nn; n += 8) {
    const int* arow = adj + ((size_t)(b * Nn + n)) * (2 * Nn);
    const float* srow = &sm[n * Nn];
#pragma unroll
    for (int which = 0; which < 2; which++) {
      const int* am = arow + which * Nn;
      float* dst = (which ? simout : simin) + ((size_t)(b * Nn + n)) * Nn;
      int m1 = lane + 64;
      float x0 = (am[lane] > 0) ? srow[lane] : -9e15f;
      float x1 = (m1 < Nn) ? ((am[m1] > 0) ? srow[m1] : -9e15f) : -INFINITY;
      float mx = fmaxf(x0, x1);
#pragma unroll
      for (int o = 32; o; o >>= 1) mx = fmaxf(mx, __shfl_xor(mx, o));
      float e0 = __expf(x0 - mx);
      float e1 = (m1 < Nn) ? __expf(x1 - mx) : 0.f;
      float s = e0 + e1;
#pragma unroll
      for (int o = 32; o; o >>= 1) s += __shfl_xor(s, o);
      float inv = 1.f / s;
      dst[lane] = e0 * inv;
      if (m1 < Nn) dst[m1] = e1 * inv;
    }
  }
}

// ---------------- graph mixing: input_in/out -> concat buffer ----------------
__global__ __launch_bounds__(256) void k_mix(const float* __restrict__ simin,
                                             const float* __restrict__ simout,
                                             const float* __restrict__ ain,
                                             const float* __restrict__ aout,
                                             const float* __restrict__ biah,
                                             const float* __restrict__ boah,
                                             float* __restrict__ inmix) {
  int bn = blockIdx.x;
  int h = threadIdx.x;
  int b = bn / Nn;
  const float* Si = simin + (size_t)bn * Nn;
  const float* So = simout + (size_t)bn * Nn;
  const float* Ai = ain + (size_t)b * Nn * 256;
  const float* Ao = aout + (size_t)b * Nn * 256;
  float si = 0.f, so = 0.f;
  for (int m = 0; m < Nn; m++) {
    si += Si[m] * Ai[m * 256 + h];
    so += So[m] * Ao[m * 256 + h];
  }
  inmix[(size_t)bn * 512 + h] = si + biah[h];
  inmix[(size_t)bn * 512 + 256 + h] = so + boah[h];
}

extern "C" void kernel_launch(void* const* d_in, const int* in_sizes, int n_in,
                              void* d_out, int out_size, void* d_ws, size_t ws_size,
                              hipStream_t stream) {
  (void)in_sizes; (void)n_in; (void)out_size; (void)ws_size;
  const float* h_local = (const float*)d_in[0];
  const float* items   = (const float*)d_in[1];
  const int*   adj     = (const int*)d_in[2];
  const float* bn_g  = (const float*)d_in[4];
  const float* bn_b  = (const float*)d_in[5];
  const float* W_q = (const float*)d_in[6];   const float* b_q = (const float*)d_in[7];
  const float* W_k = (const float*)d_in[8];   const float* b_k = (const float*)d_in[9];
  const float* W_v = (const float*)d_in[10];  const float* b_v = (const float*)d_in[11];
  const float* W_f = (const float*)d_in[12];  const float* b_f = (const float*)d_in[13];
  const float* W_fc = (const float*)d_in[14]; const float* b_fc = (const float*)d_in[15];
  const float* W_in = (const float*)d_in[16]; const float* b_in = (const float*)d_in[17];
  const float* W_out = (const float*)d_in[18]; const float* b_out = (const float*)d_in[19];
  const float* b_iah = (const float*)d_in[20]; const float* b_oah = (const float*)d_in[21];
  const float* W_io = (const float*)d_in[22];  const float* b_io = (const float*)d_in[23];
  float* out = (float*)d_out;

  char* w = (char*)d_ws;
  auto alloc = [&](size_t bytes) { char* p = w; w += (bytes + 255) & ~(size_t)255; return p; };
  unsigned short* Mb = (unsigned short*)alloc((size_t)DP * DP * 2);
  float* G      = (float*)alloc((size_t)Dd * 304 * 4);
  float* uv     = (float*)alloc(304 * 4);
  float* tv     = (float*)alloc(304 * 4);
  float* cv     = (float*)alloc(256);
  float* bias2  = (float*)alloc(304 * 4);
  float* r_all  = (float*)alloc((size_t)NBLK * 304 * 4);
  float* colsum = (float*)alloc((size_t)NBLK * 304 * 4);
  float* hrev   = (float*)alloc((size_t)NBLK * 304 * 4);
  float* hidden = (float*)alloc((size_t)NBLK * 256 * 4);
  float* ain    = (float*)alloc((size_t)NBLK * 256 * 4);
  float* aout   = (float*)alloc((size_t)NBLK * 256 * 4);
  float* simin  = (float*)alloc((size_t)Bb * Nn * Nn * 4);
  float* simout = (float*)alloc((size_t)Bb * Nn * Nn * 4);
  float* inmix  = (float*)alloc((size_t)NBLK * 512 * 4);

  k_matM<<<(DP * DP + 255) / 256, 256, 0, stream>>>(W_q, W_k, Mb);
  k_matG<<<(Dd * 304 + 255) / 256, 256, 0, stream>>>(W_f, W_v, G);
  k_vec<<<1, 512, 0, stream>>>(W_q, W_k, W_f, b_q, b_k, b_v, b_f, uv, tv, cv, bias2);
  k_attn<<<NBLK, 512, 0, stream>>>(items, Mb, uv, tv, cv, r_all, colsum);
  {
    dim3 g(25, 5);
    k_gemm_bt<<<g, 256, 0, stream>>>(r_all, 304, G, 304, bias2, colsum, 304,
                                     hrev, 304, NBLK, 300, 304, nullptr, nullptr);
  }
  k_sim<<<Bb, 512, 0, stream>>>(hrev, adj, simin, simout);
  {
    dim3 g(25, 4);
    k_gemm_bt<<<g, 256, 0, stream>>>(h_local, 256, W_fc, 256, b_fc, nullptr, 0,
                                     hidden, 256, NBLK, 256, 256, bn_g, bn_b);
    k_gemm_bt<<<g, 256, 0, stream>>>(hidden, 256, W_in, 256, b_in, nullptr, 0,
                                     ain, 256, NBLK, 256, 256, nullptr, nullptr);
    k_gemm_bt<<<g, 256, 0, stream>>>(hidden, 256, W_out, 256, b_out, nullptr, 0,
                                     aout, 256, NBLK, 256, 256, nullptr, nullptr);
  }
  k_mix<<<NBLK, 256, 0, stream>>>(simin, simout, ain, aout, b_iah, b_oah, inmix);
  {
    dim3 g(25, 4);
    k_gemm_bt<<<g, 256, 0, stream>>>(inmix, 512, W_io, 512, b_io, nullptr, 0,
                                     out, 256, NBLK, 256, 512, nullptr, nullptr);
  }
}

// Round 3
// 775.838 us; speedup vs baseline: 1.4319x; 1.4319x over previous
//
#include <hip/hip_runtime.h>
#include <math.h>

#define Bb 16
#define Nn 100
#define Ll 90
#define Dd 300
#define NBLK (Bb*Nn)
#define LP 96
#define DP 320
#define DPH 40   // DP/8 16-byte chunks per row

typedef __attribute__((ext_vector_type(8))) short short8v;
typedef __attribute__((ext_vector_type(4))) short short4v;
typedef __attribute__((ext_vector_type(4))) float f32x4;

__device__ __forceinline__ unsigned short f2bf(float f) {
  unsigned int u = __float_as_uint(f);
  u += 0x7fffu + ((u >> 16) & 1u);
  return (unsigned short)(u >> 16);
}
__device__ __forceinline__ float bf2f(unsigned short h) {
  return __uint_as_float(((unsigned int)h) << 16);
}

// ---------------- setup kernels ----------------
// M[i][j] = sum_o Wq[o][i]*Wk[o][j], bf16, padded to 320x320 with zeros
__global__ __launch_bounds__(256) void k_matM(const float* __restrict__ Wq,
                                              const float* __restrict__ Wk,
                                              unsigned short* __restrict__ Mb) {
  int idx = blockIdx.x * 256 + threadIdx.x;
  if (idx >= DP * DP) return;
  int i = idx / DP, j = idx % DP;
  float s = 0.f;
  if (i < Dd && j < Dd) {
    for (int o = 0; o < Dd; o++) s += Wq[o * Dd + i] * Wk[o * Dd + j];
  }
  Mb[idx] = f2bf(s);
}

// G[o][p] = sum_v Wf[o][v]*Wv[v][p], f32, [300][304] (pad cols zero)
__global__ __launch_bounds__(256) void k_matG(const float* __restrict__ Wf,
                                              const float* __restrict__ Wv,
                                              float* __restrict__ G) {
  int idx = blockIdx.x * 256 + threadIdx.x;
  if (idx >= Dd * 304) return;
  int o = idx / 304, p = idx % 304;
  float s = 0.f;
  if (p < Dd) {
    for (int v = 0; v < Dd; v++) s += Wf[o * Dd + v] * Wv[v * Dd + p];
  }
  G[idx] = s;
}

// u = Wq^T b_k, t = Wk^T b_q, c = b_q.b_k, bias2 = 90*(Wf b_v + b_f)
__global__ void k_vec(const float* __restrict__ Wq, const float* __restrict__ Wk,
                      const float* __restrict__ Wf,
                      const float* __restrict__ bq, const float* __restrict__ bk,
                      const float* __restrict__ bv, const float* __restrict__ bf,
                      float* __restrict__ uv, float* __restrict__ tv,
                      float* __restrict__ cv, float* __restrict__ bias2) {
  int t = threadIdx.x;
  if (t < 304) {
    float su = 0.f, st = 0.f, sb = 0.f;
    if (t < Dd) {
      for (int o = 0; o < Dd; o++) {
        su += Wq[o * Dd + t] * bk[o];
        st += Wk[o * Dd + t] * bq[o];
      }
      for (int v = 0; v < Dd; v++) sb += Wf[t * Dd + v] * bv[v];
      sb = 90.f * (sb + bf[t]);
    }
    uv[t] = su; tv[t] = st; bias2[t] = sb;
  }
  if (t == 511) {
    float s = 0.f;
    for (int o = 0; o < Dd; o++) s += bq[o] * bk[o];
    cv[0] = s;
  }
}

// C[z] = A[z] * B[z] (256x256 each), optional column scale by gamma*rsqrt(1+1e-5)
__global__ __launch_bounds__(256) void k_mm256(
    const float* __restrict__ A0, const float* __restrict__ A1, int lda,
    const float* __restrict__ B0, const float* __restrict__ B1, int ldb,
    float* __restrict__ C, int ldc, const float* __restrict__ gamma) {
  const float* A = blockIdx.z ? A1 : A0;
  const float* B = blockIdx.z ? B1 : B0;
  float* Cb = C + (size_t)blockIdx.z * 256 * ldc;
  __shared__ float As[16][68];
  __shared__ float Bs[16][68];
  int m0 = blockIdx.x * 64, n0 = blockIdx.y * 64;
  int tx = threadIdx.x & 15, ty = threadIdx.x >> 4;
  float acc[4][4];
#pragma unroll
  for (int i = 0; i < 4; i++)
#pragma unroll
    for (int j = 0; j < 4; j++) acc[i][j] = 0.f;
  int r = threadIdx.x >> 2;
  int kq = (threadIdx.x & 3) << 2;
  int kk2 = threadIdx.x >> 4;
  int nq = (threadIdx.x & 15) << 2;
  for (int k0 = 0; k0 < 256; k0 += 16) {
    {
      float4 v = *(const float4*)(A + (size_t)(m0 + r) * lda + k0 + kq);
      As[kq + 0][r] = v.x; As[kq + 1][r] = v.y; As[kq + 2][r] = v.z; As[kq + 3][r] = v.w;
    }
    {
      float4 v = *(const float4*)(B + (size_t)(k0 + kk2) * ldb + n0 + nq);
      Bs[kk2][nq + 0] = v.x; Bs[kk2][nq + 1] = v.y; Bs[kk2][nq + 2] = v.z; Bs[kk2][nq + 3] = v.w;
    }
    __syncthreads();
#pragma unroll
    for (int kk = 0; kk < 16; kk++) {
      float4 av = *(const float4*)&As[kk][ty * 4];
      float4 bv = *(const float4*)&Bs[kk][tx * 4];
      acc[0][0] += av.x * bv.x; acc[0][1] += av.x * bv.y; acc[0][2] += av.x * bv.z; acc[0][3] += av.x * bv.w;
      acc[1][0] += av.y * bv.x; acc[1][1] += av.y * bv.y; acc[1][2] += av.y * bv.z; acc[1][3] += av.y * bv.w;
      acc[2][0] += av.z * bv.x; acc[2][1] += av.z * bv.y; acc[2][2] += av.z * bv.z; acc[2][3] += av.z * bv.w;
      acc[3][0] += av.w * bv.x; acc[3][1] += av.w * bv.y; acc[3][2] += av.w * bv.z; acc[3][3] += av.w * bv.w;
    }
    __syncthreads();
  }
  const float bninv = rsqrtf(1.00001f);
#pragma unroll
  for (int i = 0; i < 4; i++) {
    int gm = m0 + ty * 4 + i;
#pragma unroll
    for (int j = 0; j < 4; j++) {
      int gn = n0 + tx * 4 + j;
      float v = acc[i][j];
      if (gamma) v *= gamma[gn] * bninv;
      Cb[(size_t)gm * ldc + gn] = v;
    }
  }
}

// d = WL*(W_in*(W_fc*beta + b_fc) + b_in + b_iah) + WR*(...) + b_io
__global__ __launch_bounds__(256) void k_vecd(
    const float* __restrict__ W_fc, const float* __restrict__ b_fc,
    const float* __restrict__ beta,
    const float* __restrict__ W_in, const float* __restrict__ b_in,
    const float* __restrict__ b_iah,
    const float* __restrict__ W_out, const float* __restrict__ b_out,
    const float* __restrict__ b_oah,
    const float* __restrict__ W_io, const float* __restrict__ b_io,
    float* __restrict__ dvec) {
  __shared__ float v1[256];
  __shared__ float v23[512];
  int i = threadIdx.x;
  float s = 0.f;
  for (int k = 0; k < 256; k++) s += W_fc[i * 256 + k] * beta[k];
  v1[i] = s + b_fc[i];
  __syncthreads();
  float s2 = 0.f, s3 = 0.f;
  for (int k = 0; k < 256; k++) {
    float vk = v1[k];
    s2 += W_in[i * 256 + k] * vk;
    s3 += W_out[i * 256 + k] * vk;
  }
  v23[i] = s2 + b_in[i] + b_iah[i];
  v23[256 + i] = s3 + b_out[i] + b_oah[i];
  __syncthreads();
  float sd = 0.f;
  for (int k = 0; k < 512; k++) sd += W_io[i * 512 + k] * v23[k];
  dvec[i] = sd + b_io[i];
}

// ---------------- per-(b,n) attention kernel (2 blocks/CU) ----------------
__global__ __launch_bounds__(512, 4) void k_attn(
    const float* __restrict__ items, const unsigned short* __restrict__ Mb,
    const float* __restrict__ uvec, const float* __restrict__ tvec,
    const float* __restrict__ cval_p,
    float* __restrict__ r_all, float* __restrict__ colsum_all) {
  __shared__ unsigned short Xs[LP * DP];   // 61440 B
  __shared__ unsigned short Zc[LP * 64];   // 12288 B
  __shared__ float ulv[LP], tmv[LP], wsum[LP];
  __shared__ float ulds[304], tlds[304];

  const int tid = threadIdx.x;
  const int bid = blockIdx.x;
  const float* Xg = items + (size_t)bid * (Ll * Dd);
  const float cval = cval_p[0];

  // P0: stage X -> LDS bf16 swizzled, stage u/t, colsum, zero wsum
  for (int c = tid; c < LP * DPH; c += 512) {
    int l = c / DPH, ch = c % DPH, d0 = ch * 8;
    float v[8];
    if (l < Ll && d0 < Dd) {
      if (d0 + 8 <= Dd) {
        float4 a = *(const float4*)(Xg + l * Dd + d0);
        float4 b = *(const float4*)(Xg + l * Dd + d0 + 4);
        v[0] = a.x; v[1] = a.y; v[2] = a.z; v[3] = a.w;
        v[4] = b.x; v[5] = b.y; v[6] = b.z; v[7] = b.w;
      } else {
#pragma unroll
        for (int q = 0; q < 8; q++) { int d = d0 + q; v[q] = (d < Dd) ? Xg[l * Dd + d] : 0.f; }
      }
    } else {
#pragma unroll
      for (int q = 0; q < 8; q++) v[q] = 0.f;
    }
    short8v pk;
#pragma unroll
    for (int q = 0; q < 8; q++) pk[q] = (short)f2bf(v[q]);
    *(short8v*)((char*)Xs + l * 640 + ((d0 * 2) ^ ((l & 7) << 4))) = pk;
  }
  for (int d = tid; d < 304; d += 512) { ulds[d] = uvec[d]; tlds[d] = tvec[d]; }
  if (tid < LP) wsum[tid] = 0.f;
  for (int d = tid; d < 304; d += 512) {
    float s = 0.f;
    if (d < Dd) {
      for (int l = 0; l < Ll; l++) s += Xg[l * Dd + d];
    }
    colsum_all[(size_t)bid * 304 + d] = s;
  }
  __syncthreads();

  // P1: ulv[l]=X[l].u, tmv[m]=X[m].t  (4 threads per row)
  if (tid < 384) {
    int row = tid >> 2, q = tid & 3;
    float su = 0.f, st = 0.f;
    if (row < Ll) {
      for (int ii = 0; ii < 75; ii++) {
        int i = q * 75 + ii;
        float xv = bf2f(Xs[(row * 640 + ((i * 2) ^ ((row & 7) << 4))) >> 1]);
        su += xv * ulds[i];
        st += xv * tlds[i];
      }
    }
    su += __shfl_xor(su, 1); su += __shfl_xor(su, 2);
    st += __shfl_xor(st, 1); st += __shfl_xor(st, 2);
    if (q == 0) { ulv[row] = su; tmv[row] = st; }
  }
  __syncthreads();

  const int lane = tid & 63, wave = tid >> 6;
  const int fr = lane & 15, kg = lane >> 4;

  f32x4 acc[6];
#pragma unroll
  for (int mt = 0; mt < 6; mt++) acc[mt] = (f32x4){0.f, 0.f, 0.f, 0.f};

  // chunked S = X M X^T over i-chunks of 64
  for (int c = 0; c < 5; c++) {
    // G1: Zc[m][ic] = sum_j M[c*64+ic][j] X[m][j]
    for (int t = wave; t < 24; t += 8) {
      int ict = t / 6, mt = t % 6;
      int irow = c * 64 + ict * 16 + fr;
      f32x4 zacc = (f32x4){0.f, 0.f, 0.f, 0.f};
#pragma unroll
      for (int ks = 0; ks < 10; ks++) {
        short8v a = *(const short8v*)(Mb + irow * DP + ks * 32 + kg * 8);
        int brow = mt * 16 + fr;
        short8v b = *(const short8v*)((char*)Xs + brow * 640 +
                                      (((ks * 32 + kg * 8) * 2) ^ ((brow & 7) << 4)));
        zacc = __builtin_amdgcn_mfma_f32_16x16x32_bf16(a, b, zacc, 0, 0, 0);
      }
      int m = mt * 16 + fr;
      int ic0 = ict * 16 + kg * 4;
      short4v pk;
#pragma unroll
      for (int r2 = 0; r2 < 4; r2++) pk[r2] = (short)f2bf(zacc[r2]);
      *(short4v*)((char*)Zc + m * 128 + ((ic0 * 2) ^ ((m & 7) << 4))) = pk;
    }
    __syncthreads();
    // G2: S += X[:,chunk] * Zc^T ; wave w owns row-tile lt=w
    if (wave < 6) {
#pragma unroll
      for (int mt = 0; mt < 6; mt++) {
#pragma unroll
        for (int ks = 0; ks < 2; ks++) {
          int arow = wave * 16 + fr;
          short8v a = *(const short8v*)((char*)Xs + arow * 640 +
                                        (((c * 64 + ks * 32 + kg * 8) * 2) ^ ((arow & 7) << 4)));
          int brow = mt * 16 + fr;
          short8v b = *(const short8v*)((char*)Zc + brow * 128 +
                                        (((ks * 32 + kg * 8) * 2) ^ ((brow & 7) << 4)));
          acc[mt] = __builtin_amdgcn_mfma_f32_16x16x32_bf16(a, b, acc[mt], 0, 0, 0);
        }
      }
    }
    __syncthreads();
  }

  // P3: in-register row softmax + column sums
  if (wave < 6) {
    float tmc[6];
#pragma unroll
    for (int mt = 0; mt < 6; mt++) tmc[mt] = tmv[mt * 16 + fr];
    float colpart[6] = {0.f, 0.f, 0.f, 0.f, 0.f, 0.f};
#pragma unroll
    for (int r2 = 0; r2 < 4; r2++) {
      int l = wave * 16 + kg * 4 + r2;
      float base = ulv[l] + cval;
      float x[6];
#pragma unroll
      for (int mt = 0; mt < 6; mt++) {
        int col = mt * 16 + fr;
        x[mt] = (col < Ll) ? 0.1f * (acc[mt][r2] + base + tmc[mt]) : -INFINITY;
      }
      float mx = x[0];
#pragma unroll
      for (int mt = 1; mt < 6; mt++) mx = fmaxf(mx, x[mt]);
      mx = fmaxf(mx, __shfl_xor(mx, 1));
      mx = fmaxf(mx, __shfl_xor(mx, 2));
      mx = fmaxf(mx, __shfl_xor(mx, 4));
      mx = fmaxf(mx, __shfl_xor(mx, 8));
      float e[6]; float s = 0.f;
#pragma unroll
      for (int mt = 0; mt < 6; mt++) { e[mt] = __expf(x[mt] - mx); s += e[mt]; }
      s += __shfl_xor(s, 1); s += __shfl_xor(s, 2);
      s += __shfl_xor(s, 4); s += __shfl_xor(s, 8);
      float inv = 1.f / s;
      if (l < Ll) {
#pragma unroll
        for (int mt = 0; mt < 6; mt++) colpart[mt] += e[mt] * inv;
      }
    }
#pragma unroll
    for (int mt = 0; mt < 6; mt++) {
      colpart[mt] += __shfl_xor(colpart[mt], 16);
      colpart[mt] += __shfl_xor(colpart[mt], 32);
    }
    if (lane < 16) {
#pragma unroll
      for (int mt = 0; mt < 6; mt++) atomicAdd(&wsum[mt * 16 + fr], colpart[mt]);
    }
  }
  __syncthreads();

  // P4: r[i] = sum_m wsum[m] X[m][i]
  for (int i = tid; i < 304; i += 512) {
    float s = 0.f;
    if (i < Dd) {
      for (int m = 0; m < Ll; m++)
        s += wsum[m] * bf2f(Xs[(m * 640 + ((i * 2) ^ ((m & 7) << 4))) >> 1]);
    }
    r_all[(size_t)bid * 304 + i] = s;
  }
}

// ---------------- generic f32 GEMM: C = A @ W^T + bias (+res) ----------------
__global__ __launch_bounds__(256) void k_gemm_bt(
    const float* __restrict__ A, int lda, const float* __restrict__ W, int ldw,
    const float* __restrict__ bias, const float* __restrict__ res, int ldres,
    float* __restrict__ C, int ldc, int Mdim, int Ndim, int Kdim) {
  __shared__ float As[16][68];
  __shared__ float Bs[16][68];
  int m0 = blockIdx.x * 64, n0 = blockIdx.y * 64;
  int tx = threadIdx.x & 15, ty = threadIdx.x >> 4;
  float acc[4][4];
#pragma unroll
  for (int i = 0; i < 4; i++)
#pragma unroll
    for (int j = 0; j < 4; j++) acc[i][j] = 0.f;
  int r = threadIdx.x >> 2;
  int kq = (threadIdx.x & 3) << 2;
  for (int k0 = 0; k0 < Kdim; k0 += 16) {
    {
      int gm = m0 + r;
      float4 v = {0.f, 0.f, 0.f, 0.f};
      if (gm < Mdim) v = *(const float4*)(A + (size_t)gm * lda + k0 + kq);
      As[kq + 0][r] = v.x; As[kq + 1][r] = v.y; As[kq + 2][r] = v.z; As[kq + 3][r] = v.w;
    }
    {
      int gn = n0 + r;
      float4 v = {0.f, 0.f, 0.f, 0.f};
      if (gn < Ndim) v = *(const float4*)(W + (size_t)gn * ldw + k0 + kq);
      Bs[kq + 0][r] = v.x; Bs[kq + 1][r] = v.y; Bs[kq + 2][r] = v.z; Bs[kq + 3][r] = v.w;
    }
    __syncthreads();
#pragma unroll
    for (int kk = 0; kk < 16; kk++) {
      float4 av = *(const float4*)&As[kk][ty * 4];
      float4 bv = *(const float4*)&Bs[kk][tx * 4];
      acc[0][0] += av.x * bv.x; acc[0][1] += av.x * bv.y; acc[0][2] += av.x * bv.z; acc[0][3] += av.x * bv.w;
      acc[1][0] += av.y * bv.x; acc[1][1] += av.y * bv.y; acc[1][2] += av.y * bv.z; acc[1][3] += av.y * bv.w;
      acc[2][0] += av.z * bv.x; acc[2][1] += av.z * bv.y; acc[2][2] += av.z * bv.z; acc[2][3] += av.z * bv.w;
      acc[3][0] += av.w * bv.x; acc[3][1] += av.w * bv.y; acc[3][2] += av.w * bv.z; acc[3][3] += av.w * bv.w;
    }
    __syncthreads();
  }
#pragma unroll
  for (int i = 0; i < 4; i++) {
    int gm = m0 + ty * 4 + i;
    if (gm >= Mdim) continue;
#pragma unroll
    for (int j = 0; j < 4; j++) {
      int gn = n0 + tx * 4 + j;
      if (gn >= Ndim) continue;
      float v = acc[i][j];
      if (bias) v += bias[gn];
      if (res) v += res[(size_t)gm * ldres + gn];
      C[(size_t)gm * ldc + gn] = v;
    }
  }
}

// ---------------- normalize hrev rows -> bf16 [1600][320] ----------------
__global__ __launch_bounds__(256) void k_norm(const float* __restrict__ hrev,
                                              unsigned short* __restrict__ Hn) {
  int row = blockIdx.x * 4 + (threadIdx.x >> 6);
  int lane = threadIdx.x & 63;
  float v[5]; float ss = 0.f;
#pragma unroll
  for (int j = 0; j < 5; j++) {
    int i = lane + j * 64;
    float x = (i < Dd) ? hrev[(size_t)row * 304 + i] : 0.f;
    v[j] = x; ss += x * x;
  }
#pragma unroll
  for (int o = 32; o; o >>= 1) ss += __shfl_xor(ss, o);
  float inv = (ss > 0.f) ? rsqrtf(ss) : 0.f;
#pragma unroll
  for (int j = 0; j < 5; j++) {
    int i = lane + j * 64;
    if (i < DP) Hn[(size_t)row * DP + i] = f2bf(v[j] * inv);
  }
}

// ---------------- per-batch cosine gram (MFMA) + masked double softmax ----------------
__global__ __launch_bounds__(512) void k_simgram(
    const unsigned short* __restrict__ Hn, const int* __restrict__ adj,
    float* __restrict__ simin, float* __restrict__ simout) {
  __shared__ unsigned short HL[112 * DP];  // 71680 B
  int b = blockIdx.x, tid = threadIdx.x;
  for (int c = tid; c < 112 * DPH; c += 512) {
    int rb = c / DPH, ch = c % DPH;
    short8v v;
    if (rb < Nn) v = *(const short8v*)(Hn + ((size_t)(b * Nn + rb)) * DP + ch * 8);
    else {
#pragma unroll
      for (int q = 0; q < 8; q++) v[q] = 0;
    }
    *(short8v*)((char*)HL + rb * 640 + ((ch * 16) ^ ((rb & 7) << 4))) = v;
  }
  __syncthreads();
  const int lane = tid & 63, wave = tid >> 6;
  const int fr = lane & 15, kg = lane >> 4;
  if (wave < 7) {
    f32x4 acc[7];
#pragma unroll
    for (int mt = 0; mt < 7; mt++) acc[mt] = (f32x4){0.f, 0.f, 0.f, 0.f};
#pragma unroll
    for (int mt = 0; mt < 7; mt++) {
#pragma unroll
      for (int ks = 0; ks < 10; ks++) {
        int ar = wave * 16 + fr;
        short8v a = *(const short8v*)((char*)HL + ar * 640 +
                                      (((ks * 32 + kg * 8) * 2) ^ ((ar & 7) << 4)));
        int br = mt * 16 + fr;
        short8v bb = *(const short8v*)((char*)HL + br * 640 +
                                       (((ks * 32 + kg * 8) * 2) ^ ((br & 7) << 4)));
        acc[mt] = __builtin_amdgcn_mfma_f32_16x16x32_bf16(a, bb, acc[mt], 0, 0, 0);
      }
    }
    const int* adjb = adj + (size_t)b * Nn * 2 * Nn;
#pragma unroll
    for (int which = 0; which < 2; which++) {
      float* dst = which ? simout : simin;
#pragma unroll
      for (int r2 = 0; r2 < 4; r2++) {
        int l = wave * 16 + kg * 4 + r2;
        bool lv = l < Nn;
        float x[7];
#pragma unroll
        for (int mt = 0; mt < 7; mt++) {
          int col = mt * 16 + fr;
          bool cvd = col < Nn;
          int am = (lv && cvd) ? adjb[l * (2 * Nn) + which * Nn + col] : 0;
          x[mt] = cvd ? ((am > 0) ? acc[mt][r2] : -9e15f) : -INFINITY;
        }
        float mx = x[0];
#pragma unroll
        for (int mt = 1; mt < 7; mt++) mx = fmaxf(mx, x[mt]);
        mx = fmaxf(mx, __shfl_xor(mx, 1));
        mx = fmaxf(mx, __shfl_xor(mx, 2));
        mx = fmaxf(mx, __shfl_xor(mx, 4));
        mx = fmaxf(mx, __shfl_xor(mx, 8));
        float e[7]; float s = 0.f;
#pragma unroll
        for (int mt = 0; mt < 7; mt++) { e[mt] = __expf(x[mt] - mx); s += e[mt]; }
        s += __shfl_xor(s, 1); s += __shfl_xor(s, 2);
        s += __shfl_xor(s, 4); s += __shfl_xor(s, 8);
        float inv = 1.f / s;
        if (lv) {
#pragma unroll
          for (int mt = 0; mt < 7; mt++) {
            int col = mt * 16 + fr;
            if (col < Nn) dst[((size_t)(b * Nn + l)) * Nn + col] = e[mt] * inv;
          }
        }
      }
    }
  }
}

// ---------------- final: out = simin@Pin + simout@Pout + d ----------------
__global__ __launch_bounds__(256) void k_mixout(
    const float* __restrict__ simin, const float* __restrict__ simout,
    const float* __restrict__ P, const float* __restrict__ dvec,
    float* __restrict__ out) {
  __shared__ float si[Nn], so[Nn];
  int bn = blockIdx.x, h = threadIdx.x, b = bn / Nn;
  if (h < Nn) {
    si[h] = simin[(size_t)bn * Nn + h];
    so[h] = simout[(size_t)bn * Nn + h];
  }
  __syncthreads();
  const float* Pb = P + (size_t)b * Nn * 512;
  float acc = dvec[h];
  for (int m = 0; m < Nn; m++)
    acc += si[m] * Pb[m * 512 + h] + so[m] * Pb[m * 512 + 256 + h];
  out[(size_t)bn * 256 + h] = acc;
}

extern "C" void kernel_launch(void* const* d_in, const int* in_sizes, int n_in,
                              void* d_out, int out_size, void* d_ws, size_t ws_size,
                              hipStream_t stream) {
  (void)in_sizes; (void)n_in; (void)out_size; (void)ws_size;
  const float* h_local = (const float*)d_in[0];
  const float* items   = (const float*)d_in[1];
  const int*   adj     = (const int*)d_in[2];
  const float* bn_g  = (const float*)d_in[4];
  const float* bn_b  = (const float*)d_in[5];
  const float* W_q = (const float*)d_in[6];   const float* b_q = (const float*)d_in[7];
  const float* W_k = (const float*)d_in[8];   const float* b_k = (const float*)d_in[9];
  const float* W_v = (const float*)d_in[10];  const float* b_v = (const float*)d_in[11];
  const float* W_f = (const float*)d_in[12];  const float* b_f = (const float*)d_in[13];
  const float* W_fc = (const float*)d_in[14]; const float* b_fc = (const float*)d_in[15];
  const float* W_in = (const float*)d_in[16]; const float* b_in = (const float*)d_in[17];
  const float* W_out = (const float*)d_in[18]; const float* b_out = (const float*)d_in[19];
  const float* b_iah = (const float*)d_in[20]; const float* b_oah = (const float*)d_in[21];
  const float* W_io = (const float*)d_in[22];  const float* b_io = (const float*)d_in[23];
  float* out = (float*)d_out;

  char* w = (char*)d_ws;
  auto alloc = [&](size_t bytes) { char* p = w; w += (bytes + 255) & ~(size_t)255; return p; };
  unsigned short* Mb = (unsigned short*)alloc((size_t)DP * DP * 2);
  float* G      = (float*)alloc((size_t)Dd * 304 * 4);
  float* uv     = (float*)alloc(304 * 4);
  float* tv     = (float*)alloc(304 * 4);
  float* cv     = (float*)alloc(256);
  float* bias2  = (float*)alloc(304 * 4);
  float* Tbuf   = (float*)alloc((size_t)512 * 256 * 4);
  float* Bcat   = (float*)alloc((size_t)512 * 256 * 4);
  float* dvec   = (float*)alloc(256 * 4);
  float* r_all  = (float*)alloc((size_t)NBLK * 304 * 4);
  float* colsum = (float*)alloc((size_t)NBLK * 304 * 4);
  float* hrev   = (float*)alloc((size_t)NBLK * 304 * 4);
  unsigned short* Hn = (unsigned short*)alloc((size_t)NBLK * DP * 2);
  float* simin  = (float*)alloc((size_t)NBLK * Nn * 4);
  float* simout = (float*)alloc((size_t)NBLK * Nn * 4);
  float* P      = (float*)alloc((size_t)NBLK * 512 * 4);

  // setup
  k_matM<<<(DP * DP + 255) / 256, 256, 0, stream>>>(W_q, W_k, Mb);
  k_matG<<<(Dd * 304 + 255) / 256, 256, 0, stream>>>(W_f, W_v, G);
  k_vec<<<1, 512, 0, stream>>>(W_q, W_k, W_f, b_q, b_k, b_v, b_f, uv, tv, cv, bias2);
  {
    dim3 g(4, 4, 2);
    // Tbuf[0]=W_in*W_fc, Tbuf[1]=W_out*W_fc
    k_mm256<<<g, 256, 0, stream>>>(W_in, W_out, 256, W_fc, W_fc, 256, Tbuf, 256, nullptr);
    // Bcat[0:256]=WL*T1*diag(g'), Bcat[256:512]=WR*T2*diag(g')
    k_mm256<<<g, 256, 0, stream>>>(W_io, W_io + 256, 512, Tbuf, Tbuf + 256 * 256, 256,
                                   Bcat, 256, bn_g);
  }
  k_vecd<<<1, 256, 0, stream>>>(W_fc, b_fc, bn_b, W_in, b_in, b_iah,
                                W_out, b_out, b_oah, W_io, b_io, dvec);

  // P = h_local @ Bcat^T  [1600 x 512]
  {
    dim3 g(25, 8);
    k_gemm_bt<<<g, 256, 0, stream>>>(h_local, 256, Bcat, 256, nullptr, nullptr, 0,
                                     P, 512, NBLK, 512, 256);
  }

  // attention
  k_attn<<<NBLK, 512, 0, stream>>>(items, Mb, uv, tv, cv, r_all, colsum);
  {
    dim3 g(25, 5);
    k_gemm_bt<<<g, 256, 0, stream>>>(r_all, 304, G, 304, bias2, colsum, 304,
                                     hrev, 304, NBLK, 300, 304);
  }
  k_norm<<<NBLK / 4, 256, 0, stream>>>(hrev, Hn);
  k_simgram<<<Bb, 512, 0, stream>>>(Hn, adj, simin, simout);
  k_mixout<<<NBLK, 256, 0, stream>>>(simin, simout, P, dvec, out);
}

// Round 8
// 747.166 us; speedup vs baseline: 1.4869x; 1.0384x over previous
//
#include <hip/hip_runtime.h>
#include <math.h>

#define Bb 16
#define Nn 100
#define Ll 90
#define Dd 300
#define NBLK (Bb*Nn)
#define LP 96
#define DP 320
#define DPH 40   // DP/8 16-byte chunks per row

typedef __attribute__((ext_vector_type(8))) short short8v;
typedef __attribute__((ext_vector_type(4))) short short4v;
typedef __attribute__((ext_vector_type(4))) float f32x4;

__device__ __forceinline__ unsigned short f2bf(float f) {
  unsigned int u = __float_as_uint(f);
  u += 0x7fffu + ((u >> 16) & 1u);
  return (unsigned short)(u >> 16);
}
__device__ __forceinline__ float bf2f(unsigned short h) {
  return __uint_as_float(((unsigned int)h) << 16);
}

// ---------------- fused setup ----------------
// blocks 0..399:   M'[i][j] (bf16, 320x320): i,j<300 -> Wq^T Wk ; col 300 -> u=Wq^T bk ;
//                  row 300 -> t=Wk^T bq ; (300,300) -> bq.bk ; rest 0
// blocks 400..756: G[o][p] = (Wf Wv)[o][p], f32 [300][304]
// block 757:       bias2[o] = 90*(Wf bv + bf)[o]
__global__ __launch_bounds__(256) void k_setup(
    const float* __restrict__ Wq, const float* __restrict__ Wk,
    const float* __restrict__ bq, const float* __restrict__ bk,
    const float* __restrict__ Wf, const float* __restrict__ Wv,
    const float* __restrict__ bv, const float* __restrict__ bf,
    unsigned short* __restrict__ Mb, float* __restrict__ G,
    float* __restrict__ bias2) {
  int blk = blockIdx.x;
  if (blk < 400) {
    int idx = blk * 256 + threadIdx.x;
    int i = idx / DP, j = idx % DP;
    float s = 0.f;
    if (i <= Dd && j <= Dd) {
#pragma unroll 10
      for (int o = 0; o < Dd; o++) {
        float av = (i < Dd) ? Wq[o * Dd + i] : bq[o];
        float bw = (j < Dd) ? Wk[o * Dd + j] : bk[o];
        s += av * bw;
      }
    }
    Mb[idx] = f2bf(s);
  } else if (blk < 757) {
    int idx = (blk - 400) * 256 + threadIdx.x;
    if (idx < Dd * 304) {
      int o = idx / 304, p = idx % 304;
      float s = 0.f;
      if (p < Dd) {
#pragma unroll 10
        for (int v = 0; v < Dd; v++) s += Wf[o * Dd + v] * Wv[v * Dd + p];
      }
      G[idx] = s;
    }
  } else {
    for (int t = threadIdx.x; t < 304; t += 256) {
      float sb = 0.f;
      if (t < Dd) {
#pragma unroll 10
        for (int v = 0; v < Dd; v++) sb += Wf[t * Dd + v] * bv[v];
        sb = 90.f * (sb + bf[t]);
      }
      bias2[t] = sb;
    }
  }
}

// C[z] = A[z] * B[z] (256x256 each), optional column scale by gamma*rsqrt(1+1e-5)
__global__ __launch_bounds__(256) void k_mm256(
    const float* __restrict__ A0, const float* __restrict__ A1, int lda,
    const float* __restrict__ B0, const float* __restrict__ B1, int ldb,
    float* __restrict__ C, int ldc, const float* __restrict__ gamma) {
  const float* A = blockIdx.z ? A1 : A0;
  const float* B = blockIdx.z ? B1 : B0;
  float* Cb = C + (size_t)blockIdx.z * 256 * ldc;
  __shared__ float As[16][68];
  __shared__ float Bs[16][68];
  int m0 = blockIdx.x * 64, n0 = blockIdx.y * 64;
  int tx = threadIdx.x & 15, ty = threadIdx.x >> 4;
  float acc[4][4];
#pragma unroll
  for (int i = 0; i < 4; i++)
#pragma unroll
    for (int j = 0; j < 4; j++) acc[i][j] = 0.f;
  int r = threadIdx.x >> 2;
  int kq = (threadIdx.x & 3) << 2;
  int kk2 = threadIdx.x >> 4;
  int nq = (threadIdx.x & 15) << 2;
  for (int k0 = 0; k0 < 256; k0 += 16) {
    {
      float4 v = *(const float4*)(A + (size_t)(m0 + r) * lda + k0 + kq);
      As[kq + 0][r] = v.x; As[kq + 1][r] = v.y; As[kq + 2][r] = v.z; As[kq + 3][r] = v.w;
    }
    {
      float4 v = *(const float4*)(B + (size_t)(k0 + kk2) * ldb + n0 + nq);
      Bs[kk2][nq + 0] = v.x; Bs[kk2][nq + 1] = v.y; Bs[kk2][nq + 2] = v.z; Bs[kk2][nq + 3] = v.w;
    }
    __syncthreads();
#pragma unroll
    for (int kk = 0; kk < 16; kk++) {
      float4 av = *(const float4*)&As[kk][ty * 4];
      float4 bv = *(const float4*)&Bs[kk][tx * 4];
      acc[0][0] += av.x * bv.x; acc[0][1] += av.x * bv.y; acc[0][2] += av.x * bv.z; acc[0][3] += av.x * bv.w;
      acc[1][0] += av.y * bv.x; acc[1][1] += av.y * bv.y; acc[1][2] += av.y * bv.z; acc[1][3] += av.y * bv.w;
      acc[2][0] += av.z * bv.x; acc[2][1] += av.z * bv.y; acc[2][2] += av.z * bv.z; acc[2][3] += av.z * bv.w;
      acc[3][0] += av.w * bv.x; acc[3][1] += av.w * bv.y; acc[3][2] += av.w * bv.z; acc[3][3] += av.w * bv.w;
    }
    __syncthreads();
  }
  const float bninv = rsqrtf(1.00001f);
#pragma unroll
  for (int i = 0; i < 4; i++) {
    int gm = m0 + ty * 4 + i;
#pragma unroll
    for (int j = 0; j < 4; j++) {
      int gn = n0 + tx * 4 + j;
      float v = acc[i][j];
      if (gamma) v *= gamma[gn] * bninv;
      Cb[(size_t)gm * ldc + gn] = v;
    }
  }
}

// d = WL*(W_in*(W_fc*beta + b_fc) + b_in + b_iah) + WR*(...) + b_io
__global__ __launch_bounds__(256) void k_vecd(
    const float* __restrict__ W_fc, const float* __restrict__ b_fc,
    const float* __restrict__ beta,
    const float* __restrict__ W_in, const float* __restrict__ b_in,
    const float* __restrict__ b_iah,
    const float* __restrict__ W_out, const float* __restrict__ b_out,
    const float* __restrict__ b_oah,
    const float* __restrict__ W_io, const float* __restrict__ b_io,
    float* __restrict__ dvec) {
  __shared__ float v1[256];
  __shared__ float v23[512];
  int i = threadIdx.x;
  float s = 0.f;
#pragma unroll 16
  for (int k = 0; k < 256; k++) s += W_fc[i * 256 + k] * beta[k];
  v1[i] = s + b_fc[i];
  __syncthreads();
  float s2 = 0.f, s3 = 0.f;
#pragma unroll 16
  for (int k = 0; k < 256; k++) {
    float vk = v1[k];
    s2 += W_in[i * 256 + k] * vk;
    s3 += W_out[i * 256 + k] * vk;
  }
  v23[i] = s2 + b_in[i] + b_iah[i];
  v23[256 + i] = s3 + b_out[i] + b_oah[i];
  __syncthreads();
  float sd = 0.f;
#pragma unroll 16
  for (int k = 0; k < 512; k++) sd += W_io[i * 512 + k] * v23[k];
  dvec[i] = sd + b_io[i];
}

// ---------------- per-(b,n) attention kernel ----------------
// S' = X' M' X'^T with X'[l][300]=1 folds in all bias terms.
__global__ __launch_bounds__(512, 4) void k_attn(
    const float* __restrict__ items, const unsigned short* __restrict__ Mb,
    float* __restrict__ r_all, float* __restrict__ colsum_all) {
  __shared__ unsigned short Xs[LP * DP];   // 61440 B, bf16 swizzled
  __shared__ unsigned short Zc[LP * 64];   // 12288 B
  __shared__ float wsum[LP];

  const int tid = threadIdx.x;
  const int bid = blockIdx.x;
  const float* Xg = items + (size_t)bid * (Ll * Dd);

  if (tid < LP) wsum[tid] = 0.f;

  // P0a: stage X' -> LDS bf16 swizzled, zero-padded to [96][320], col 300 = 1.0
  for (int c = tid; c < LP * DPH; c += 512) {
    int l = c / DPH, ch = c % DPH, d0 = ch * 8;
    float v[8];
    if (l < Ll && d0 < Dd) {
      if (d0 + 8 <= Dd) {
        float4 a = *(const float4*)(Xg + l * Dd + d0);
        float4 b = *(const float4*)(Xg + l * Dd + d0 + 4);
        v[0] = a.x; v[1] = a.y; v[2] = a.z; v[3] = a.w;
        v[4] = b.x; v[5] = b.y; v[6] = b.z; v[7] = b.w;
      } else {
#pragma unroll
        for (int q = 0; q < 8; q++) {
          int d = d0 + q;
          v[q] = (d < Dd) ? Xg[l * Dd + d] : ((d == Dd) ? 1.f : 0.f);
        }
      }
    } else {
#pragma unroll
      for (int q = 0; q < 8; q++) v[q] = 0.f;
    }
    short8v pk;
#pragma unroll
    for (int q = 0; q < 8; q++) pk[q] = (short)f2bf(v[q]);
    *(short8v*)((char*)Xs + l * 640 + ((d0 * 2) ^ ((l & 7) << 4))) = pk;
  }

  // P0b: colsum(X) exact f32 from global, deep-pipelined
  for (int d = tid; d < 304; d += 512) {
    float s = 0.f;
    if (d < Dd) {
#pragma unroll 18
      for (int l = 0; l < Ll; l++) s += Xg[l * Dd + d];
    }
    colsum_all[(size_t)bid * 304 + d] = s;
  }
  __syncthreads();

  const int lane = tid & 63, wave = tid >> 6;
  const int fr = lane & 15, kg = lane >> 4;

  // G1 tile descriptors: tile t = wave + 8*tt, t<24; ict=t/6 (i-subtile), mt=t%6 (m-tile)
  int itile[3], bbyte[3], bswz[3], mrow[3], icol0[3];
#pragma unroll
  for (int tt = 0; tt < 3; tt++) {
    int t = wave + tt * 8;
    int ict = t / 6, mt = t - ict * 6;
    itile[tt] = ict * 16 + fr;
    int brow = mt * 16 + fr;
    bbyte[tt] = brow * 640;
    bswz[tt] = (brow & 7) << 4;
    mrow[tt] = brow;
    icol0[tt] = ict * 16 + kg * 4;
  }

  f32x4 acc[6];
#pragma unroll
  for (int mt = 0; mt < 6; mt++) acc[mt] = (f32x4){0.f, 0.f, 0.f, 0.f};

  // chunked S = X' M' X'^T over i-chunks of 64
  for (int c = 0; c < 5; c++) {
    // G1: Zc[m][ic] = sum_j M'[c*64+ic][j] X'[m][j]  (3-way MFMA ILP)
    f32x4 z0 = (f32x4){0.f, 0.f, 0.f, 0.f}, z1 = z0, z2 = z0;
    const unsigned short* MbC = Mb + (size_t)(c * 64) * DP;
#pragma unroll
    for (int ks = 0; ks < 10; ks++) {
      int koff = ks * 32 + kg * 8;
      short8v a0 = *(const short8v*)(MbC + itile[0] * DP + koff);
      short8v b0 = *(const short8v*)((char*)Xs + bbyte[0] + ((koff * 2) ^ bswz[0]));
      z0 = __builtin_amdgcn_mfma_f32_16x16x32_bf16(a0, b0, z0, 0, 0, 0);
      short8v a1 = *(const short8v*)(MbC + itile[1] * DP + koff);
      short8v b1 = *(const short8v*)((char*)Xs + bbyte[1] + ((koff * 2) ^ bswz[1]));
      z1 = __builtin_amdgcn_mfma_f32_16x16x32_bf16(a1, b1, z1, 0, 0, 0);
      short8v a2 = *(const short8v*)(MbC + itile[2] * DP + koff);
      short8v b2 = *(const short8v*)((char*)Xs + bbyte[2] + ((koff * 2) ^ bswz[2]));
      z2 = __builtin_amdgcn_mfma_f32_16x16x32_bf16(a2, b2, z2, 0, 0, 0);
    }
#pragma unroll
    for (int tt = 0; tt < 3; tt++) {
      f32x4 z = tt == 0 ? z0 : (tt == 1 ? z1 : z2);
      short4v pk;
#pragma unroll
      for (int r2 = 0; r2 < 4; r2++) pk[r2] = (short)f2bf(z[r2]);
      *(short4v*)((char*)Zc + mrow[tt] * 128 +
                  ((icol0[tt] * 2) ^ ((mrow[tt] & 7) << 4))) = pk;
    }
    __syncthreads();
    // G2: S += X'[:,chunk] * Zc^T ; wave w (<6) owns row-tile w
    if (wave < 6) {
      int arow = wave * 16 + fr;
      int abyte = arow * 640, aswz = (arow & 7) << 4;
#pragma unroll
      for (int mt = 0; mt < 6; mt++) {
        int brow = mt * 16 + fr;
#pragma unroll
        for (int ks = 0; ks < 2; ks++) {
          short8v a = *(const short8v*)((char*)Xs + abyte +
                                        (((c * 64 + ks * 32 + kg * 8) * 2) ^ aswz));
          short8v b = *(const short8v*)((char*)Zc + brow * 128 +
                                        (((ks * 32 + kg * 8) * 2) ^ ((brow & 7) << 4)));
          acc[mt] = __builtin_amdgcn_mfma_f32_16x16x32_bf16(a, b, acc[mt], 0, 0, 0);
        }
      }
    }
    __syncthreads();
  }

  // P3: in-register row softmax + column sums
  if (wave < 6) {
    float colpart[6] = {0.f, 0.f, 0.f, 0.f, 0.f, 0.f};
#pragma unroll
    for (int r2 = 0; r2 < 4; r2++) {
      int l = wave * 16 + kg * 4 + r2;
      float x[6];
#pragma unroll
      for (int mt = 0; mt < 6; mt++) {
        int col = mt * 16 + fr;
        x[mt] = (col < Ll) ? 0.1f * acc[mt][r2] : -INFINITY;
      }
      float mx = x[0];
#pragma unroll
      for (int mt = 1; mt < 6; mt++) mx = fmaxf(mx, x[mt]);
      mx = fmaxf(mx, __shfl_xor(mx, 1));
      mx = fmaxf(mx, __shfl_xor(mx, 2));
      mx = fmaxf(mx, __shfl_xor(mx, 4));
      mx = fmaxf(mx, __shfl_xor(mx, 8));
      float e[6]; float s = 0.f;
#pragma unroll
      for (int mt = 0; mt < 6; mt++) { e[mt] = __expf(x[mt] - mx); s += e[mt]; }
      s += __shfl_xor(s, 1); s += __shfl_xor(s, 2);
      s += __shfl_xor(s, 4); s += __shfl_xor(s, 8);
      float inv = 1.f / s;
      if (l < Ll) {
#pragma unroll
        for (int mt = 0; mt < 6; mt++) colpart[mt] += e[mt] * inv;
      }
    }
#pragma unroll
    for (int mt = 0; mt < 6; mt++) {
      colpart[mt] += __shfl_xor(colpart[mt], 16);
      colpart[mt] += __shfl_xor(colpart[mt], 32);
    }
    if (lane < 16) {
#pragma unroll
      for (int mt = 0; mt < 6; mt++) atomicAdd(&wsum[mt * 16 + fr], colpart[mt]);
    }
  }
  __syncthreads();

  // P4: r[i] = sum_m wsum[m] X[m][i]  (pipelined LDS reads)
  for (int i = tid; i < 304; i += 512) {
    float s = 0.f;
    if (i < Dd) {
#pragma unroll 15
      for (int m = 0; m < Ll; m++)
        s += wsum[m] * bf2f(Xs[(m * 640 + ((i * 2) ^ ((m & 7) << 4))) >> 1]);
    }
    r_all[(size_t)bid * 304 + i] = s;
  }
}

// ---------------- generic f32 GEMM: C = A @ W^T + bias (+res) ----------------
__global__ __launch_bounds__(256) void k_gemm_bt(
    const float* __restrict__ A, int lda, const float* __restrict__ W, int ldw,
    const float* __restrict__ bias, const float* __restrict__ res, int ldres,
    float* __restrict__ C, int ldc, int Mdim, int Ndim, int Kdim) {
  __shared__ float As[16][68];
  __shared__ float Bs[16][68];
  int m0 = blockIdx.x * 64, n0 = blockIdx.y * 64;
  int tx = threadIdx.x & 15, ty = threadIdx.x >> 4;
  float acc[4][4];
#pragma unroll
  for (int i = 0; i < 4; i++)
#pragma unroll
    for (int j = 0; j < 4; j++) acc[i][j] = 0.f;
  int r = threadIdx.x >> 2;
  int kq = (threadIdx.x & 3) << 2;
  for (int k0 = 0; k0 < Kdim; k0 += 16) {
    {
      int gm = m0 + r;
      float4 v = {0.f, 0.f, 0.f, 0.f};
      if (gm < Mdim) v = *(const float4*)(A + (size_t)gm * lda + k0 + kq);
      As[kq + 0][r] = v.x; As[kq + 1][r] = v.y; As[kq + 2][r] = v.z; As[kq + 3][r] = v.w;
    }
    {
      int gn = n0 + r;
      float4 v = {0.f, 0.f, 0.f, 0.f};
      if (gn < Ndim) v = *(const float4*)(W + (size_t)gn * ldw + k0 + kq);
      Bs[kq + 0][r] = v.x; Bs[kq + 1][r] = v.y; Bs[kq + 2][r] = v.z; Bs[kq + 3][r] = v.w;
    }
    __syncthreads();
#pragma unroll
    for (int kk = 0; kk < 16; kk++) {
      float4 av = *(const float4*)&As[kk][ty * 4];
      float4 bv = *(const float4*)&Bs[kk][tx * 4];
      acc[0][0] += av.x * bv.x; acc[0][1] += av.x * bv.y; acc[0][2] += av.x * bv.z; acc[0][3] += av.x * bv.w;
      acc[1][0] += av.y * bv.x; acc[1][1] += av.y * bv.y; acc[1][2] += av.y * bv.z; acc[1][3] += av.y * bv.w;
      acc[2][0] += av.z * bv.x; acc[2][1] += av.z * bv.y; acc[2][2] += av.z * bv.z; acc[2][3] += av.z * bv.w;
      acc[3][0] += av.w * bv.x; acc[3][1] += av.w * bv.y; acc[3][2] += av.w * bv.z; acc[3][3] += av.w * bv.w;
    }
    __syncthreads();
  }
#pragma unroll
  for (int i = 0; i < 4; i++) {
    int gm = m0 + ty * 4 + i;
    if (gm >= Mdim) continue;
#pragma unroll
    for (int j = 0; j < 4; j++) {
      int gn = n0 + tx * 4 + j;
      if (gn >= Ndim) continue;
      float v = acc[i][j];
      if (bias) v += bias[gn];
      if (res) v += res[(size_t)gm * ldres + gn];
      C[(size_t)gm * ldc + gn] = v;
    }
  }
}

// ---------------- normalize hrev rows -> bf16 [1600][320] ----------------
__global__ __launch_bounds__(256) void k_norm(const float* __restrict__ hrev,
                                              unsigned short* __restrict__ Hn) {
  int row = blockIdx.x * 4 + (threadIdx.x >> 6);
  int lane = threadIdx.x & 63;
  float v[5]; float ss = 0.f;
#pragma unroll
  for (int j = 0; j < 5; j++) {
    int i = lane + j * 64;
    float x = (i < Dd) ? hrev[(size_t)row * 304 + i] : 0.f;
    v[j] = x; ss += x * x;
  }
#pragma unroll
  for (int o = 32; o; o >>= 1) ss += __shfl_xor(ss, o);
  float inv = (ss > 0.f) ? rsqrtf(ss) : 0.f;
#pragma unroll
  for (int j = 0; j < 5; j++) {
    int i = lane + j * 64;
    if (i < DP) Hn[(size_t)row * DP + i] = f2bf(v[j] * inv);
  }
}

// ---------------- cosine gram row-strip + masked double softmax ----------------
// grid (Bb, 7): block = 1 wave, computes rows rt*16..rt*16+15 vs all 100 cols,
// MFMA fragments straight from L2-resident Hn.
__global__ __launch_bounds__(64) void k_simgram(
    const unsigned short* __restrict__ Hn, const int* __restrict__ adj,
    float* __restrict__ simin, float* __restrict__ simout) {
  int b = blockIdx.x, rt = blockIdx.y;
  int lane = threadIdx.x;
  int fr = lane & 15, kg = lane >> 4;
  const unsigned short* Hb = Hn + (size_t)b * Nn * DP;
  int ar = rt * 16 + fr;
  short8v zerov;
#pragma unroll
  for (int q = 0; q < 8; q++) zerov[q] = 0;
  f32x4 acc[7];
#pragma unroll
  for (int mt = 0; mt < 7; mt++) acc[mt] = (f32x4){0.f, 0.f, 0.f, 0.f};
#pragma unroll
  for (int ks = 0; ks < 10; ks++) {
    int koff = ks * 32 + kg * 8;
    short8v a = (ar < Nn) ? *(const short8v*)(Hb + (size_t)ar * DP + koff) : zerov;
#pragma unroll
    for (int mt = 0; mt < 7; mt++) {
      int br = mt * 16 + fr;
      short8v bb = (br < Nn) ? *(const short8v*)(Hb + (size_t)br * DP + koff) : zerov;
      acc[mt] = __builtin_amdgcn_mfma_f32_16x16x32_bf16(a, bb, acc[mt], 0, 0, 0);
    }
  }
  const int* adjb = adj + (size_t)b * Nn * 2 * Nn;
#pragma unroll
  for (int which = 0; which < 2; which++) {
    float* dst = which ? simout : simin;
#pragma unroll
    for (int r2 = 0; r2 < 4; r2++) {
      int l = rt * 16 + kg * 4 + r2;
      bool lv = l < Nn;
      float x[7];
#pragma unroll
      for (int mt = 0; mt < 7; mt++) {
        int col = mt * 16 + fr;
        bool cvd = col < Nn;
        int am = (lv && cvd) ? adjb[l * (2 * Nn) + which * Nn + col] : 0;
        x[mt] = cvd ? ((am > 0) ? acc[mt][r2] : -9e15f) : -INFINITY;
      }
      float mx = x[0];
#pragma unroll
      for (int mt = 1; mt < 7; mt++) mx = fmaxf(mx, x[mt]);
      mx = fmaxf(mx, __shfl_xor(mx, 1));
      mx = fmaxf(mx, __shfl_xor(mx, 2));
      mx = fmaxf(mx, __shfl_xor(mx, 4));
      mx = fmaxf(mx, __shfl_xor(mx, 8));
      float e[7]; float s = 0.f;
#pragma unroll
      for (int mt = 0; mt < 7; mt++) { e[mt] = __expf(x[mt] - mx); s += e[mt]; }
      s += __shfl_xor(s, 1); s += __shfl_xor(s, 2);
      s += __shfl_xor(s, 4); s += __shfl_xor(s, 8);
      float inv = 1.f / s;
      if (lv) {
#pragma unroll
        for (int mt = 0; mt < 7; mt++) {
          int col = mt * 16 + fr;
          if (col < Nn) dst[((size_t)(b * Nn + l)) * Nn + col] = e[mt] * inv;
        }
      }
    }
  }
}

// ---------------- final: out = simin@Pin + simout@Pout + d ----------------
__global__ __launch_bounds__(256) void k_mixout(
    const float* __restrict__ simin, const float* __restrict__ simout,
    const float* __restrict__ P, const float* __restrict__ dvec,
    float* __restrict__ out) {
  __shared__ float si[Nn], so[Nn];
  int bn = blockIdx.x, h = threadIdx.x, b = bn / Nn;
  if (h < Nn) {
    si[h] = simin[(size_t)bn * Nn + h];
    so[h] = simout[(size_t)bn * Nn + h];
  }
  __syncthreads();
  const float* Pb = P + (size_t)b * Nn * 512;
  float acc = dvec[h];
#pragma unroll 10
  for (int m = 0; m < Nn; m++)
    acc += si[m] * Pb[m * 512 + h] + so[m] * Pb[m * 512 + 256 + h];
  out[(size_t)bn * 256 + h] = acc;
}

extern "C" void kernel_launch(void* const* d_in, const int* in_sizes, int n_in,
                              void* d_out, int out_size, void* d_ws, size_t ws_size,
                              hipStream_t stream) {
  (void)in_sizes; (void)n_in; (void)out_size; (void)ws_size;
  const float* h_local = (const float*)d_in[0];
  const float* items   = (const float*)d_in[1];
  const int*   adj     = (const int*)d_in[2];
  const float* bn_g  = (const float*)d_in[4];
  const float* bn_b  = (const float*)d_in[5];
  const float* W_q = (const float*)d_in[6];   const float* b_q = (const float*)d_in[7];
  const float* W_k = (const float*)d_in[8];   const float* b_k = (const float*)d_in[9];
  const float* W_v = (const float*)d_in[10];  const float* b_v = (const float*)d_in[11];
  const float* W_f = (const float*)d_in[12];  const float* b_f = (const float*)d_in[13];
  const float* W_fc = (const float*)d_in[14]; const float* b_fc = (const float*)d_in[15];
  const float* W_in = (const float*)d_in[16]; const float* b_in = (const float*)d_in[17];
  const float* W_out = (const float*)d_in[18]; const float* b_out = (const float*)d_in[19];
  const float* b_iah = (const float*)d_in[20]; const float* b_oah = (const float*)d_in[21];
  const float* W_io = (const float*)d_in[22];  const float* b_io = (const float*)d_in[23];
  float* out = (float*)d_out;

  char* w = (char*)d_ws;
  auto alloc = [&](size_t bytes) { char* p = w; w += (bytes + 255) & ~(size_t)255; return p; };
  unsigned short* Mb = (unsigned short*)alloc((size_t)DP * DP * 2);
  float* G      = (float*)alloc((size_t)Dd * 304 * 4);
  float* bias2  = (float*)alloc(304 * 4);
  float* Tbuf   = (float*)alloc((size_t)512 * 256 * 4);
  float* Bcat   = (float*)alloc((size_t)512 * 256 * 4);
  float* dvec   = (float*)alloc(256 * 4);
  float* r_all  = (float*)alloc((size_t)NBLK * 304 * 4);
  float* colsum = (float*)alloc((size_t)NBLK * 304 * 4);
  float* hrev   = (float*)alloc((size_t)NBLK * 304 * 4);
  unsigned short* Hn = (unsigned short*)alloc((size_t)NBLK * DP * 2);
  float* simin  = (float*)alloc((size_t)NBLK * Nn * 4);
  float* simout = (float*)alloc((size_t)NBLK * Nn * 4);
  float* P      = (float*)alloc((size_t)NBLK * 512 * 4);

  // fused setup: M' (with u/t/c folded), G, bias2
  k_setup<<<758, 256, 0, stream>>>(W_q, W_k, b_q, b_k, W_f, W_v, b_v, b_f,
                                   Mb, G, bias2);
  // attention (long pole) right after its dependency
  k_attn<<<NBLK, 512, 0, stream>>>(items, Mb, r_all, colsum);

  {
    dim3 g(4, 4, 2);
    k_mm256<<<g, 256, 0, stream>>>(W_in, W_out, 256, W_fc, W_fc, 256, Tbuf, 256, nullptr);
    k_mm256<<<g, 256, 0, stream>>>(W_io, W_io + 256, 512, Tbuf, Tbuf + 256 * 256, 256,
                                   Bcat, 256, bn_g);
  }
  k_vecd<<<1, 256, 0, stream>>>(W_fc, b_fc, bn_b, W_in, b_in, b_iah,
                                W_out, b_out, b_oah, W_io, b_io, dvec);
  {
    dim3 g(25, 8);
    k_gemm_bt<<<g, 256, 0, stream>>>(h_local, 256, Bcat, 256, nullptr, nullptr, 0,
                                     P, 512, NBLK, 512, 256);
  }
  {
    dim3 g(25, 5);
    k_gemm_bt<<<g, 256, 0, stream>>>(r_all, 304, G, 304, bias2, colsum, 304,
                                     hrev, 304, NBLK, 300, 304);
  }
  k_norm<<<NBLK / 4, 256, 0, stream>>>(hrev, Hn);
  {
    dim3 g(Bb, 7);
    k_simgram<<<g, 64, 0, stream>>>(Hn, adj, simin, simout);
  }
  k_mixout<<<NBLK, 256, 0, stream>>>(simin, simout, P, dvec, out);
}